// Round 2
// baseline (69.429 us; speedup 1.0000x reference)
//
#include <hip/hip_runtime.h>

// RNN(tanh) fused forward: xin-proj + scan + fc + exp in one kernel.
// T=512, B=32768, H=2, IN=2, OUT=1. One thread per batch element.
// Latency-bound regime (0.5 waves/SIMD) -> 32-deep rotating load pipeline.

#define T_STEPS 512
#define BATCH   32768
#define PF      32   // prefetch depth (timesteps of x in flight)

typedef float v2f __attribute__((ext_vector_type(2)));

__global__ __launch_bounds__(64) void rnn_fused_kernel(
    const v2f*   __restrict__ x,     // [T][B] as float2 (n_in=2)
    const float* __restrict__ W_ih,  // [2][2]
    const float* __restrict__ W_hh,  // [2][2]
    const float* __restrict__ b_ih,  // [2]
    const float* __restrict__ b_hh,  // [2]
    const float* __restrict__ fc_w,  // [1][2]
    const float* __restrict__ fc_b,  // [1]
    float*       __restrict__ out)   // [T*B] output, then [B][2] h_last
{
    const int b = blockIdx.x * 64 + threadIdx.x;

    const float L2E = 1.44269504088896340736f;   // log2(e)
    const float S   = 2.0f * L2E;
    // Pre-scale so a' = 2*log2e*a comes straight out of the fma chain.
    const float w00 = W_ih[0]*S, w01 = W_ih[1]*S, w10 = W_ih[2]*S, w11 = W_ih[3]*S;
    const float u00 = W_hh[0]*S, u01 = W_hh[1]*S, u10 = W_hh[2]*S, u11 = W_hh[3]*S;
    const float bi0 = (b_ih[0] + b_hh[0])*S, bi1 = (b_ih[1] + b_hh[1])*S;
    const float f0 = fc_w[0]*L2E, f1 = fc_w[1]*L2E, fb = fc_b[0]*L2E;

    const v2f* xp = x + b;
    float* op = out + b;

    float h0 = 0.0f, h1 = 0.0f;

    v2f buf[PF];
    #pragma unroll
    for (int i = 0; i < PF; ++i)
        buf[i] = __builtin_nontemporal_load(&xp[(size_t)i * BATCH]);

    for (int t0 = 0; t0 < T_STEPS; t0 += PF) {
        #pragma unroll
        for (int i = 0; i < PF; ++i) {
            const float x0 = buf[i].x, x1 = buf[i].y;

            // x-only part of the pre-activation (h-independent, off critical path)
            float a0 = fmaf(x0, w00, fmaf(x1, w01, bi0));
            float a1 = fmaf(x0, w10, fmaf(x1, w11, bi1));

            // re-issue this slot's load PF steps ahead (clamped at tail; uniform idx)
            int tld = t0 + i + PF;
            tld = tld < T_STEPS ? tld : T_STEPS - 1;
            buf[i] = __builtin_nontemporal_load(&xp[(size_t)tld * BATCH]);

            // recurrent contribution (critical path: 2 dependent fmas)
            a0 = fmaf(h1, u01, a0);  a0 = fmaf(h0, u00, a0);
            a1 = fmaf(h0, u10, a1);  a1 = fmaf(h1, u11, a1);

            // tanh(a) = 1 - 2/(exp2(a')+1), a' pre-scaled
            const float e0 = __builtin_amdgcn_exp2f(a0);
            const float e1 = __builtin_amdgcn_exp2f(a1);
            h0 = fmaf(-2.0f, __builtin_amdgcn_rcpf(e0 + 1.0f), 1.0f);
            h1 = fmaf(-2.0f, __builtin_amdgcn_rcpf(e1 + 1.0f), 1.0f);

            // fused projection + exp (off critical path)
            const float z = fmaf(h0, f0, fmaf(h1, f1, fb));
            __builtin_nontemporal_store(__builtin_amdgcn_exp2f(z),
                                        &op[(size_t)(t0 + i) * BATCH]);
        }
    }

    // h_last: [1][B][2] — one coalesced 8B store per lane
    v2f hv; hv.x = h0; hv.y = h1;
    ((v2f*)(out + (size_t)T_STEPS * BATCH))[b] = hv;
}

extern "C" void kernel_launch(void* const* d_in, const int* in_sizes, int n_in,
                              void* d_out, int out_size, void* d_ws, size_t ws_size,
                              hipStream_t stream) {
    const v2f*   x    = (const v2f*)d_in[0];
    const float* W_ih = (const float*)d_in[1];
    const float* W_hh = (const float*)d_in[2];
    const float* b_ih = (const float*)d_in[3];
    const float* b_hh = (const float*)d_in[4];
    const float* fc_w = (const float*)d_in[5];
    const float* fc_b = (const float*)d_in[6];
    float* out = (float*)d_out;

    rnn_fused_kernel<<<dim3(BATCH / 64), dim3(64), 0, stream>>>(
        x, W_ih, W_hh, b_ih, b_hh, fc_w, fc_b, out);
}

// Round 3
// 60.768 us; speedup vs baseline: 1.1425x; 1.1425x over previous
//
#include <hip/hip_runtime.h>

// RNN(tanh) fused forward: xin-proj + scan + fc + exp in one kernel.
// T=512, B=32768, H=2, IN=2, OUT=1. One thread per batch element.
// Latency-bound regime (0.5 waves/SIMD): 32-deep rotating load pipeline.
// Loads are LLC-allocating (x = 128MB fits the 256MB Infinity Cache and is
// re-read every replay); stores are nontemporal (out never re-read).

#define T_STEPS 512
#define BATCH   32768
#define PF      32   // prefetch depth (timesteps of x in flight)

typedef float v2f __attribute__((ext_vector_type(2)));

__global__ __launch_bounds__(64) void rnn_fused_kernel(
    const v2f*   __restrict__ x,     // [T][B] as float2 (n_in=2)
    const float* __restrict__ W_ih,  // [2][2]
    const float* __restrict__ W_hh,  // [2][2]
    const float* __restrict__ b_ih,  // [2]
    const float* __restrict__ b_hh,  // [2]
    const float* __restrict__ fc_w,  // [1][2]
    const float* __restrict__ fc_b,  // [1]
    float*       __restrict__ out)   // [T*B] output, then [B][2] h_last
{
    const int b = blockIdx.x * 64 + threadIdx.x;

    const float L2E = 1.44269504088896340736f;   // log2(e)
    const float S   = 2.0f * L2E;
    // Pre-scale so a' = 2*log2e*a comes straight out of the fma chain.
    const float w00 = W_ih[0]*S, w01 = W_ih[1]*S, w10 = W_ih[2]*S, w11 = W_ih[3]*S;
    const float u00 = W_hh[0]*S, u01 = W_hh[1]*S, u10 = W_hh[2]*S, u11 = W_hh[3]*S;
    const float bi0 = (b_ih[0] + b_hh[0])*S, bi1 = (b_ih[1] + b_hh[1])*S;
    const float f0 = fc_w[0]*L2E, f1 = fc_w[1]*L2E, fb = fc_b[0]*L2E;

    const v2f* xp = x + b;
    float* op = out + b;

    float h0 = 0.0f, h1 = 0.0f;

    v2f buf[PF];
    #pragma unroll
    for (int i = 0; i < PF; ++i)
        buf[i] = xp[(size_t)i * BATCH];

    for (int t0 = 0; t0 < T_STEPS; t0 += PF) {
        #pragma unroll
        for (int i = 0; i < PF; ++i) {
            const float x0 = buf[i].x, x1 = buf[i].y;

            // x-only part of the pre-activation (h-independent, off critical path)
            float a0 = fmaf(x0, w00, fmaf(x1, w01, bi0));
            float a1 = fmaf(x0, w10, fmaf(x1, w11, bi1));

            // re-issue this slot's load PF steps ahead (clamped at tail; uniform idx)
            int tld = t0 + i + PF;
            tld = tld < T_STEPS ? tld : T_STEPS - 1;
            buf[i] = xp[(size_t)tld * BATCH];

            // recurrent contribution (critical path: 2 dependent fmas)
            a0 = fmaf(h1, u01, a0);  a0 = fmaf(h0, u00, a0);
            a1 = fmaf(h0, u10, a1);  a1 = fmaf(h1, u11, a1);

            // tanh(a) = 1 - 2/(exp2(a')+1), a' pre-scaled
            const float e0 = __builtin_amdgcn_exp2f(a0);
            const float e1 = __builtin_amdgcn_exp2f(a1);
            h0 = fmaf(-2.0f, __builtin_amdgcn_rcpf(e0 + 1.0f), 1.0f);
            h1 = fmaf(-2.0f, __builtin_amdgcn_rcpf(e1 + 1.0f), 1.0f);

            // fused projection + exp (off critical path)
            const float z = fmaf(h0, f0, fmaf(h1, f1, fb));
            __builtin_nontemporal_store(__builtin_amdgcn_exp2f(z),
                                        &op[(size_t)(t0 + i) * BATCH]);
        }
    }

    // h_last: [1][B][2] — one coalesced 8B store per lane
    v2f hv; hv.x = h0; hv.y = h1;
    __builtin_nontemporal_store(hv, (v2f*)(out + (size_t)T_STEPS * BATCH) + b);
}

extern "C" void kernel_launch(void* const* d_in, const int* in_sizes, int n_in,
                              void* d_out, int out_size, void* d_ws, size_t ws_size,
                              hipStream_t stream) {
    const v2f*   x    = (const v2f*)d_in[0];
    const float* W_ih = (const float*)d_in[1];
    const float* W_hh = (const float*)d_in[2];
    const float* b_ih = (const float*)d_in[3];
    const float* b_hh = (const float*)d_in[4];
    const float* fc_w = (const float*)d_in[5];
    const float* fc_b = (const float*)d_in[6];
    float* out = (float*)d_out;

    rnn_fused_kernel<<<dim3(BATCH / 64), dim3(64), 0, stream>>>(
        x, W_ih, W_hh, b_ih, b_hh, fc_w, fc_b, out);
}

// Round 4
// 44.474 us; speedup vs baseline: 1.5611x; 1.3664x over previous
//
#include <hip/hip_runtime.h>

// RNN(tanh) fused forward, producer-consumer wave specialization.
// T=512, B=32768, H=2. Block = 256 threads: wave 0 = consumer (64 chains,
// one per lane, h in registers), waves 1-3 = producers staging x chunks
// into a double-buffered LDS ring. Decouples HBM latency from the
// sequential recurrence; 8 waves/CU instead of 2.

#define T_STEPS 512
#define BATCH   32768
#define CH      32              // timesteps per chunk
#define NC      (T_STEPS / CH)  // 16 chunks

typedef float v2f __attribute__((ext_vector_type(2)));

__global__ __launch_bounds__(256, 2) void rnn_pc_kernel(
    const v2f*   __restrict__ x,     // [T][B] float2
    const float* __restrict__ W_ih,  // [2][2]
    const float* __restrict__ W_hh,  // [2][2]
    const float* __restrict__ b_ih,  // [2]
    const float* __restrict__ b_hh,  // [2]
    const float* __restrict__ fc_w,  // [1][2]
    const float* __restrict__ fc_b,  // [1]
    float*       __restrict__ out)   // [T*B] output, then [B][2] h_last
{
    __shared__ v2f buf[2][CH][64];

    const int tid  = threadIdx.x;
    const int wave = tid >> 6;
    const int lane = tid & 63;
    const int b    = blockIdx.x * 64 + lane;

    if (wave != 0) {
        // ---- producers: waves 1..3 stage x into the LDS ring ----
        const int w = wave - 1;             // 0..2
        const v2f* xp = x + b;

        // prologue: chunk 0 -> buf[0]
        #pragma unroll
        for (int k = 0; k < (CH + 2) / 3; ++k) {
            const int j = w + 3 * k;
            if (j < CH) buf[0][j][lane] = xp[(size_t)j * BATCH];
        }
        __syncthreads();

        for (int c = 0; c < NC; ++c) {
            if (c + 1 < NC) {
                const size_t tb = (size_t)(c + 1) * CH;
                #pragma unroll
                for (int k = 0; k < (CH + 2) / 3; ++k) {
                    const int j = w + 3 * k;
                    if (j < CH) buf[(c + 1) & 1][j][lane] = xp[(tb + j) * BATCH];
                }
            }
            __syncthreads();
        }
    } else {
        // ---- consumer: wave 0 runs the recurrence from LDS ----
        const float L2E = 1.44269504088896340736f;   // log2(e)
        const float S   = 2.0f * L2E;
        // pre-scaled weights: a' = 2*log2e*a feeds exp2 directly
        const float w00 = W_ih[0]*S, w01 = W_ih[1]*S, w10 = W_ih[2]*S, w11 = W_ih[3]*S;
        const float u00 = W_hh[0]*S, u01 = W_hh[1]*S, u10 = W_hh[2]*S, u11 = W_hh[3]*S;
        const float bi0 = (b_ih[0] + b_hh[0])*S, bi1 = (b_ih[1] + b_hh[1])*S;
        const float f0 = fc_w[0]*L2E, f1 = fc_w[1]*L2E, fb = fc_b[0]*L2E;

        float h0 = 0.0f, h1 = 0.0f;
        float* op = out + b;

        __syncthreads();   // matches producer prologue barrier

        for (int c = 0; c < NC; ++c) {
            const int tbase = c * CH;
            #pragma unroll
            for (int i = 0; i < CH; ++i) {
                const v2f xv = buf[c & 1][i][lane];

                float a0 = fmaf(xv.x, w00, fmaf(xv.y, w01, bi0));
                float a1 = fmaf(xv.x, w10, fmaf(xv.y, w11, bi1));
                a0 = fmaf(h1, u01, a0);  a0 = fmaf(h0, u00, a0);
                a1 = fmaf(h0, u10, a1);  a1 = fmaf(h1, u11, a1);

                // tanh(a) = 1 - 2/(exp2(a')+1)
                const float e0 = __builtin_amdgcn_exp2f(a0);
                const float e1 = __builtin_amdgcn_exp2f(a1);
                h0 = fmaf(-2.0f, __builtin_amdgcn_rcpf(e0 + 1.0f), 1.0f);
                h1 = fmaf(-2.0f, __builtin_amdgcn_rcpf(e1 + 1.0f), 1.0f);

                // fused projection + exp
                const float z = fmaf(h0, f0, fmaf(h1, f1, fb));
                op[(size_t)(tbase + i) * BATCH] = __builtin_amdgcn_exp2f(z);
            }
            __syncthreads();
        }

        // h_last: [1][B][2] — one 8B store per lane
        v2f hv; hv.x = h0; hv.y = h1;
        ((v2f*)(out + (size_t)T_STEPS * BATCH))[b] = hv;
    }
}

extern "C" void kernel_launch(void* const* d_in, const int* in_sizes, int n_in,
                              void* d_out, int out_size, void* d_ws, size_t ws_size,
                              hipStream_t stream) {
    const v2f*   x    = (const v2f*)d_in[0];
    const float* W_ih = (const float*)d_in[1];
    const float* W_hh = (const float*)d_in[2];
    const float* b_ih = (const float*)d_in[3];
    const float* b_hh = (const float*)d_in[4];
    const float* fc_w = (const float*)d_in[5];
    const float* fc_b = (const float*)d_in[6];
    float* out = (float*)d_out;

    rnn_pc_kernel<<<dim3(BATCH / 64), dim3(256), 0, stream>>>(
        x, W_ih, W_hh, b_ih, b_hh, fc_w, fc_b, out);
}

// Round 5
// 37.799 us; speedup vs baseline: 1.8368x; 1.1766x over previous
//
#include <hip/hip_runtime.h>

// RNN(tanh) fused forward — producer/consumer v2.
// T=512, B=32768, H=2. 256 blocks x 256 threads, 1 block/CU (128KB LDS).
// Waves 0-1: consumers, 64 chains each, one wave per SIMD (no collision).
// Waves 2-3: producers — DMA-stage x chunks via global_load_lds(16B) AND
// run the output stream (z = f·h+b, exp2, store) one chunk behind, reading
// h from a second LDS ring. Consumer touches no global memory.

#define T_STEPS 512
#define BATCH   32768
#define CH      32              // timesteps per chunk
#define NC      (T_STEPS / CH)  // 16 chunks

typedef float v2f __attribute__((ext_vector_type(2)));

__global__ __launch_bounds__(256, 1) void rnn_pc2_kernel(
    const v2f*   __restrict__ x,     // [T][B] float2
    const float* __restrict__ W_ih,  // [2][2]
    const float* __restrict__ W_hh,  // [2][2]
    const float* __restrict__ b_ih,  // [2]
    const float* __restrict__ b_hh,  // [2]
    const float* __restrict__ fc_w,  // [1][2]
    const float* __restrict__ fc_b,  // [1]
    float*       __restrict__ out)   // [T*B] output, then [B][2] h_last
{
    __shared__ v2f xbuf[2][CH][128];   // staged x, 64KB
    __shared__ v2f hbuf[2][CH][128];   // staged h, 64KB

    const int tid  = threadIdx.x;
    const int wave = tid >> 6;
    const int lane = tid & 63;
    const size_t bbase = (size_t)blockIdx.x * 128;

    const float L2E = 1.44269504088896340736f;   // log2(e)

    if (wave >= 2) {
        // ---------------- producers (waves 2,3) ----------------
        const int p = wave - 2;                  // 0,1
        const float f0 = fc_w[0]*L2E, f1 = fc_w[1]*L2E, fb = fc_b[0]*L2E;
        const int j = p * 64 + lane;             // chain owned for out-stream
        float* op = out + bbase + j;

        // prologue: DMA chunk 0 -> xbuf[0] (each producer does odd/even rows)
        #pragma unroll
        for (int k = 0; k < CH / 2; ++k) {
            const int i = 2 * k + p;
            const v2f* src = x + (size_t)i * BATCH + bbase;  // 1KB row slice
            __builtin_amdgcn_global_load_lds(
                (const __attribute__((address_space(1))) void*)(src + lane * 2),
                (__attribute__((address_space(3))) void*)&xbuf[0][i][lane * 2],
                16, 0, 0);
        }
        __syncthreads();

        for (int c = 0; c < NC; ++c) {
            // (a) DMA next chunk while consumers compute chunk c
            if (c + 1 < NC) {
                #pragma unroll
                for (int k = 0; k < CH / 2; ++k) {
                    const int i = 2 * k + p;
                    const v2f* src = x + ((size_t)(c + 1) * CH + i) * BATCH + bbase;
                    __builtin_amdgcn_global_load_lds(
                        (const __attribute__((address_space(1))) void*)(src + lane * 2),
                        (__attribute__((address_space(3))) void*)&xbuf[(c + 1) & 1][i][lane * 2],
                        16, 0, 0);
                }
            }
            // (b) output stream for chunk c-1 (h staged by consumers)
            if (c > 0) {
                const int tb = (c - 1) * CH;
                #pragma unroll
                for (int i = 0; i < CH; ++i) {
                    const v2f hv = hbuf[(c - 1) & 1][i][j];
                    const float z = fmaf(hv.x, f0, fmaf(hv.y, f1, fb));
                    op[(size_t)(tb + i) * BATCH] = __builtin_amdgcn_exp2f(z);
                }
            }
            __syncthreads();
        }
        // epilogue: output stream for the final chunk
        {
            const int tb = (NC - 1) * CH;
            #pragma unroll
            for (int i = 0; i < CH; ++i) {
                const v2f hv = hbuf[(NC - 1) & 1][i][j];
                const float z = fmaf(hv.x, f0, fmaf(hv.y, f1, fb));
                op[(size_t)(tb + i) * BATCH] = __builtin_amdgcn_exp2f(z);
            }
        }
    } else {
        // ---------------- consumers (waves 0,1) ----------------
        const float S = 2.0f * L2E;  // pre-scale: a' = 2*log2e*a feeds exp2
        const float w00 = W_ih[0]*S, w01 = W_ih[1]*S, w10 = W_ih[2]*S, w11 = W_ih[3]*S;
        const float u00 = W_hh[0]*S, u01 = W_hh[1]*S, u10 = W_hh[2]*S, u11 = W_hh[3]*S;
        const float bi0 = (b_ih[0] + b_hh[0])*S, bi1 = (b_ih[1] + b_hh[1])*S;

        const int j = wave * 64 + lane;          // chain within block
        float h0 = 0.0f, h1 = 0.0f;

        __syncthreads();   // matches producer prologue barrier

        for (int c = 0; c < NC; ++c) {
            #pragma unroll
            for (int i = 0; i < CH; ++i) {
                const v2f xv = xbuf[c & 1][i][j];

                float a0 = fmaf(xv.x, w00, fmaf(xv.y, w01, bi0));
                float a1 = fmaf(xv.x, w10, fmaf(xv.y, w11, bi1));
                a0 = fmaf(h1, u01, a0);  a0 = fmaf(h0, u00, a0);
                a1 = fmaf(h0, u10, a1);  a1 = fmaf(h1, u11, a1);

                // tanh(a) = 1 - 2/(exp2(a')+1)
                const float e0 = __builtin_amdgcn_exp2f(a0);
                const float e1 = __builtin_amdgcn_exp2f(a1);
                h0 = fmaf(-2.0f, __builtin_amdgcn_rcpf(e0 + 1.0f), 1.0f);
                h1 = fmaf(-2.0f, __builtin_amdgcn_rcpf(e1 + 1.0f), 1.0f);

                v2f hv; hv.x = h0; hv.y = h1;
                hbuf[c & 1][i][j] = hv;
            }
            __syncthreads();
        }

        // h_last: [1][B][2] — one 8B store per lane
        v2f hv; hv.x = h0; hv.y = h1;
        ((v2f*)(out + (size_t)T_STEPS * BATCH))[bbase + j] = hv;
    }
}

extern "C" void kernel_launch(void* const* d_in, const int* in_sizes, int n_in,
                              void* d_out, int out_size, void* d_ws, size_t ws_size,
                              hipStream_t stream) {
    const v2f*   x    = (const v2f*)d_in[0];
    const float* W_ih = (const float*)d_in[1];
    const float* W_hh = (const float*)d_in[2];
    const float* b_ih = (const float*)d_in[3];
    const float* b_hh = (const float*)d_in[4];
    const float* fc_w = (const float*)d_in[5];
    const float* fc_b = (const float*)d_in[6];
    float* out = (float*)d_out;

    rnn_pc2_kernel<<<dim3(BATCH / 128), dim3(256), 0, stream>>>(
        x, W_ih, W_hh, b_ih, b_hh, fc_w, fc_b, out);
}